// Round 4
// baseline (1194.108 us; speedup 1.0000x reference)
//
#include <hip/hip_runtime.h>
#include <hip/hip_bf16.h>
#include <math.h>

// Problem constants (B=4, N=S=512, C=1024, 16 heads x 64, MLP hidden 4096)
#define BDIM 4
#define SEQ 512
#define CH 1024
#define NH 16
#define HD 64
#define HIDN 4096
#define ROWS (BDIM * SEQ)      // 2048 per stream
#define MROWS (2 * ROWS)       // 4096 merged (x then y)
#define BHTOT (BDIM * NH)      // 64 per stream

using bf16 = __hip_bfloat16;
typedef __attribute__((ext_vector_type(4))) float f32x4;
typedef __attribute__((ext_vector_type(8))) short bf16x8;

typedef __attribute__((address_space(1))) const unsigned int GU32;
typedef __attribute__((address_space(3))) unsigned int LU32;

__device__ __forceinline__ void gload16(const bf16* g, bf16* l) {
  __builtin_amdgcn_global_load_lds((GU32*)g, (LU32*)l, 16, 0, 0);
}

// ---------------- LayerNorm: f32 row (1024) -> bf16 row ----------------
__global__ __launch_bounds__(256) void ln_bf16_kernel(
    const float* __restrict__ x, const float* __restrict__ g,
    const float* __restrict__ b, bf16* __restrict__ out) {
  int row = blockIdx.x;
  int t = threadIdx.x;
  const float4 v = reinterpret_cast<const float4*>(x + (size_t)row * CH)[t];
  float s = v.x + v.y + v.z + v.w;
  float s2 = v.x * v.x + v.y * v.y + v.z * v.z + v.w * v.w;
#pragma unroll
  for (int o = 32; o > 0; o >>= 1) {
    s += __shfl_down(s, o);
    s2 += __shfl_down(s2, o);
  }
  __shared__ float red[10];
  int lane = t & 63, wid = t >> 6;
  if (lane == 0) { red[wid] = s; red[4 + wid] = s2; }
  __syncthreads();
  if (t == 0) {
    float ts = red[0] + red[1] + red[2] + red[3];
    float ts2 = red[4] + red[5] + red[6] + red[7];
    float mean = ts * (1.0f / CH);
    float var = ts2 * (1.0f / CH) - mean * mean;
    red[8] = mean;
    red[9] = rsqrtf(var + 1e-5f);
  }
  __syncthreads();
  float mean = red[8], rstd = red[9];
  const float4 gv = reinterpret_cast<const float4*>(g)[t];
  const float4 bv = reinterpret_cast<const float4*>(b)[t];
  alignas(8) bf16 o4[4];
  o4[0] = __float2bfloat16((v.x - mean) * rstd * gv.x + bv.x);
  o4[1] = __float2bfloat16((v.y - mean) * rstd * gv.y + bv.y);
  o4[2] = __float2bfloat16((v.z - mean) * rstd * gv.z + bv.z);
  o4[3] = __float2bfloat16((v.w - mean) * rstd * gv.w + bv.w);
  reinterpret_cast<uint2*>(out + (size_t)row * CH)[t] = *reinterpret_cast<const uint2*>(o4);
}

// ------- head transpose: LN-out merged [2B][S][C] -> vT [2B*H][D][S] -----
__global__ __launch_bounds__(256) void head_transpose_kernel(
    const bf16* __restrict__ src, bf16* __restrict__ dst) {
  __shared__ bf16 t[32][33];
  int bh = blockIdx.z, b = bh >> 4, h = bh & 15;
  int s0 = blockIdx.x * 32, d0 = blockIdx.y * 32;
  int tx = threadIdx.x & 31, ty = threadIdx.x >> 5;
  const bf16* sp = src + ((size_t)(b * SEQ + s0)) * CH + h * HD + d0;
  for (int i = ty; i < 32; i += 8) t[i][tx] = sp[(size_t)i * CH + tx];
  __syncthreads();
  bf16* dp = dst + ((size_t)bh * HD + d0) * SEQ + s0;
  for (int i = ty; i < 32; i += 8) dp[(size_t)i * SEQ + tx] = t[tx][i];
}

// ------- weight transpose + cast: W[K][Nout] f32 -> WT[Nout][K] bf16 -----
__global__ __launch_bounds__(256) void wt_transpose_kernel(
    const float* __restrict__ W, bf16* __restrict__ WT, int K, int Nout) {
  __shared__ float t[32][33];
  int k0 = blockIdx.x * 32, n0 = blockIdx.y * 32;
  int tx = threadIdx.x & 31, ty = threadIdx.x >> 5;
  for (int i = ty; i < 32; i += 8)
    t[i][tx] = W[(size_t)(k0 + i) * Nout + n0 + tx];
  __syncthreads();
  for (int i = ty; i < 32; i += 8)
    WT[(size_t)(n0 + i) * K + k0 + tx] = __float2bfloat16(t[tx][i]);
}

// ============ pipelined MFMA GEMM: C = A[M][K] * Bt[N][K]^T ==============
// 128x128 tile, 4 waves (2x2), RING-buffer LDS, depth-(RING-1) prefetch,
// counted vmcnt (T3/T4). Slot-swizzled LDS (T2, rule 21: pre-swizzled
// global source + swizzled read; LDS dest linear for global_load_lds):
// physical 16B slot p of row r holds global k-slot p ^ (r&3).
// MODE 0: f32 out = base + dot + bias.  MODE 3: bf16 out = gelu(dot + bias).
template <int MODE, int RING>
__global__ __launch_bounds__(256) void gemm128(
    const bf16* __restrict__ A, int lda,
    const bf16* __restrict__ Bt, int ldb,
    void* __restrict__ Cout, int ldc,
    const float* __restrict__ base, const float* __restrict__ bias,
    int K) {
  int m0 = blockIdx.x * 128, n0 = blockIdx.y * 128;
  __shared__ bf16 As[RING][128 * 32];
  __shared__ bf16 Bs[RING][128 * 32];
  int tid = threadIdx.x, wid = tid >> 6, lane = tid & 63;
  int wr = wid >> 1, wc = wid & 1;
  int srow = tid >> 2;                                  // 0..63
  int scol = ((tid & 3) ^ (srow & 3)) << 3;             // pre-swizzled source col
  const bf16* ga = &A[(size_t)(m0 + srow) * lda + scol];
  const bf16* gb = &Bt[(size_t)(n0 + srow) * ldb + scol];
  int fr = lane & 15, kr = lane >> 4;
  f32x4 acc[4][4] = {};

  auto stage = [&](int b, int k0) {
    gload16(ga + k0, As[b] + tid * 8);
    gload16(ga + (size_t)64 * lda + k0, As[b] + 2048 + tid * 8);
    gload16(gb + k0, Bs[b] + tid * 8);
    gload16(gb + (size_t)64 * ldb + k0, Bs[b] + 2048 + tid * 8);
  };
  // read offset for row R, k-slot kr: R*32 + (kr ^ (R&3))*8 elements
  auto compute = [&](int b) {
    bf16x8 aF[4], bF[4];
#pragma unroll
    for (int m = 0; m < 4; ++m) {
      int R = wr * 64 + m * 16 + fr;
      aF[m] = *reinterpret_cast<const bf16x8*>(&As[b][R * 32 + ((kr ^ (R & 3)) << 3)]);
    }
#pragma unroll
    for (int n = 0; n < 4; ++n) {
      int R = wc * 64 + n * 16 + fr;
      bF[n] = *reinterpret_cast<const bf16x8*>(&Bs[b][R * 32 + ((kr ^ (R & 3)) << 3)]);
    }
#pragma unroll
    for (int m = 0; m < 4; ++m)
#pragma unroll
      for (int n = 0; n < 4; ++n)
        acc[m][n] = __builtin_amdgcn_mfma_f32_16x16x32_bf16(aF[m], bF[n], acc[m][n], 0, 0, 0);
  };

  int nt = K / 32;  // >= RING for all call sites
#pragma unroll
  for (int i = 0; i < RING - 1; ++i) stage(i, i * 32);
  for (int t = 0; t < nt; ++t) {
    int rem = nt - 1 - t;
    if (rem >= RING - 1) {
      stage((t + RING - 1) % RING, (t + RING - 1) * 32);
      if (RING == 4) asm volatile("s_waitcnt vmcnt(12)" ::: "memory");
      else           asm volatile("s_waitcnt vmcnt(8)" ::: "memory");
    } else if (rem == 2) {
      asm volatile("s_waitcnt vmcnt(8)" ::: "memory");
    } else if (rem == 1) {
      asm volatile("s_waitcnt vmcnt(4)" ::: "memory");
    } else {
      asm volatile("s_waitcnt vmcnt(0)" ::: "memory");
    }
    __builtin_amdgcn_s_barrier();
    __builtin_amdgcn_sched_barrier(0);
    compute(t % RING);
    __builtin_amdgcn_s_barrier();
  }

  // C/D layout: col = lane&15, row = (lane>>4)*4 + j
  int colL = lane & 15;
  int rbase = (lane >> 4) * 4;
#pragma unroll
  for (int n = 0; n < 4; ++n) {
    int gc = n0 + wc * 64 + n * 16 + colL;
    float bv = bias ? bias[gc] : 0.0f;
#pragma unroll
    for (int m = 0; m < 4; ++m)
#pragma unroll
      for (int j = 0; j < 4; ++j) {
        int gr = m0 + wr * 64 + m * 16 + rbase + j;
        float v = acc[m][n][j] + bv;
        size_t idx = (size_t)gr * ldc + gc;
        if (MODE == 0) {
          ((float*)Cout)[idx] = base[idx] + v;
        } else {
          float gl = 0.5f * v * (1.0f + erff(v * 0.70710678118654752f));
          ((bf16*)Cout)[idx] = __float2bfloat16(gl);
        }
      }
  }
}

// ================= fused attention (QK^T -> softmax -> PV) ===============
// grid (SEQ/128, 2*BHTOT), 512 threads (8 waves x 16 Q-rows).
// Scores held in registers (full row per wave -> in-wave softmax).
// K/V streamed in 64-col chunks via 3-ring LDS, counted vmcnt.
// P (128x512 bf16) in LDS, XOR-swizzled. xorb: kv batch = q batch ^ xorb.
__global__ __launch_bounds__(512) void attn_fused(
    const bf16* __restrict__ ln1, const bf16* __restrict__ vT,
    bf16* __restrict__ out, int xorb) {
  __shared__ bf16 kv[3][64 * 64];      // 3 x 8 KB ring (K chunks, then V chunks)
  __shared__ bf16 Pl[128 * 512];       // 128 KB
  int bh = blockIdx.y;                 // 0..127 (both streams)
  int b = bh >> 4, h = bh & 15;
  int kvb = b ^ xorb;
  int kvbh = kvb * NH + h;
  int m0 = blockIdx.x * 128;
  int tid = threadIdx.x, wid = tid >> 6, lane = tid & 63;
  int fr = lane & 15, kr = lane >> 4;
  // staging map: thread t -> row t>>3 (64 rows), dest col byte (t&7)*16,
  // source col pre-swizzled so LDS layout = linear ^ ((row&7)<<4)  [rule 21]
  int srow = tid >> 3;
  int scol8 = ((tid & 7) ^ (srow & 7)) << 3;
  const bf16* kbase = ln1 + ((size_t)(kvb * SEQ + srow)) * CH + h * HD + scol8;
  const bf16* vbase = vT + ((size_t)kvbh * HD + srow) * SEQ + scol8;

  // Q fragments: wave's 16 rows x K=64 (2 k-steps), direct from global
  int qrow = m0 + wid * 16 + fr;
  const bf16* qbase = ln1 + ((size_t)(b * SEQ) + qrow) * CH + h * HD;
  bf16x8 qF0 = *reinterpret_cast<const bf16x8*>(qbase + kr * 8);
  bf16x8 qF1 = *reinterpret_cast<const bf16x8*>(qbase + 32 + kr * 8);

  f32x4 acc[32];
#pragma unroll
  for (int n = 0; n < 32; ++n) acc[n] = (f32x4){0.f, 0.f, 0.f, 0.f};

  // ---- QK phase: 8 chunks of 64 kv-cols ----
  gload16(kbase, kv[0] + tid * 8);
  gload16(kbase + (size_t)64 * CH, kv[1] + tid * 8);
#pragma unroll
  for (int c = 0; c < 8; ++c) {
    if (c + 2 < 8) gload16(kbase + (size_t)(c + 2) * 64 * CH, kv[(c + 2) % 3] + tid * 8);
    if (c + 2 < 8)      asm volatile("s_waitcnt vmcnt(2)" ::: "memory");
    else if (c + 1 < 8) asm volatile("s_waitcnt vmcnt(1)" ::: "memory");
    else                asm volatile("s_waitcnt vmcnt(0)" ::: "memory");
    __builtin_amdgcn_s_barrier();
    __builtin_amdgcn_sched_barrier(0);
    const char* kb = (const char*)kv[c % 3];
#pragma unroll
    for (int nf = 0; nf < 4; ++nf) {
      int sl = nf * 16 + fr;
      int byt = sl * 128 + kr * 16;
      bf16x8 k0 = *reinterpret_cast<const bf16x8*>(kb + (byt ^ ((sl & 7) << 4)));
      bf16x8 k1 = *reinterpret_cast<const bf16x8*>(kb + ((byt + 64) ^ ((sl & 7) << 4)));
      acc[c * 4 + nf] = __builtin_amdgcn_mfma_f32_16x16x32_bf16(qF0, k0, acc[c * 4 + nf], 0, 0, 0);
      acc[c * 4 + nf] = __builtin_amdgcn_mfma_f32_16x16x32_bf16(qF1, k1, acc[c * 4 + nf], 0, 0, 0);
    }
    __builtin_amdgcn_s_barrier();
  }

  // ---- in-wave softmax: lane holds rows (lane>>4)*4+j, cols fr+16n ----
  float mx[4], sum[4], inv[4];
#pragma unroll
  for (int j = 0; j < 4; ++j) {
    float m = acc[0][j];
#pragma unroll
    for (int n = 1; n < 32; ++n) m = fmaxf(m, acc[n][j]);
    m = fmaxf(m, __shfl_xor(m, 1));
    m = fmaxf(m, __shfl_xor(m, 2));
    m = fmaxf(m, __shfl_xor(m, 4));
    m = fmaxf(m, __shfl_xor(m, 8));
    mx[j] = m * 0.125f;
  }
#pragma unroll
  for (int j = 0; j < 4; ++j) sum[j] = 0.f;
#pragma unroll
  for (int n = 0; n < 32; ++n)
#pragma unroll
    for (int j = 0; j < 4; ++j) {
      float p = exp2f((acc[n][j] * 0.125f - mx[j]) * 1.4426950408889634f);
      acc[n][j] = p;
      sum[j] += p;
    }
#pragma unroll
  for (int j = 0; j < 4; ++j) {
    float s = sum[j];
    s += __shfl_xor(s, 1);
    s += __shfl_xor(s, 2);
    s += __shfl_xor(s, 4);
    s += __shfl_xor(s, 8);
    inv[j] = 1.0f / s;
  }
  // write un-normalized P (<=1) to LDS, swizzled row-major [128][512]
  {
    char* pb = (char*)Pl;
#pragma unroll
    for (int n = 0; n < 32; ++n)
#pragma unroll
      for (int j = 0; j < 4; ++j) {
        int pr = wid * 16 + (lane >> 4) * 4 + j;
        int pc = fr + 16 * n;
        int byt = (pr * 1024 + pc * 2) ^ ((pr & 7) << 4);
        *reinterpret_cast<bf16*>(pb + byt) = __float2bfloat16(acc[n][j]);
      }
  }

  // ---- PV phase: O = P @ V, V streamed in 64-col (s) chunks ----
  f32x4 oacc[4] = {};
  int prow = wid * 16 + fr;
  gload16(vbase, kv[0] + tid * 8);
  gload16(vbase + 64, kv[1] + tid * 8);
#pragma unroll
  for (int c = 0; c < 8; ++c) {
    if (c + 2 < 8) gload16(vbase + (size_t)(c + 2) * 64, kv[(c + 2) % 3] + tid * 8);
    if (c + 2 < 8)      asm volatile("s_waitcnt vmcnt(2)" ::: "memory");
    else if (c + 1 < 8) asm volatile("s_waitcnt vmcnt(1)" ::: "memory");
    else                asm volatile("s_waitcnt vmcnt(0)" ::: "memory");
    __builtin_amdgcn_s_barrier();
    __builtin_amdgcn_sched_barrier(0);
    const char* vb = (const char*)kv[c % 3];
    const char* pb = (const char*)Pl;
#pragma unroll
    for (int ks = 0; ks < 2; ++ks) {
      int pby = (prow * 1024 + (c * 64 + ks * 32 + kr * 8) * 2) ^ ((prow & 7) << 4);
      bf16x8 pF = *reinterpret_cast<const bf16x8*>(pb + pby);
#pragma unroll
      for (int nf = 0; nf < 4; ++nf) {
        int dl = nf * 16 + fr;
        int vby = (dl * 128 + ks * 64 + kr * 16) ^ ((dl & 7) << 4);
        bf16x8 vF = *reinterpret_cast<const bf16x8*>(vb + vby);
        oacc[nf] = __builtin_amdgcn_mfma_f32_16x16x32_bf16(pF, vF, oacc[nf], 0, 0, 0);
      }
    }
    __builtin_amdgcn_s_barrier();
  }

  // ---- epilogue: normalize + write bf16 ----
#pragma unroll
  for (int nf = 0; nf < 4; ++nf)
#pragma unroll
    for (int j = 0; j < 4; ++j) {
      int r = m0 + wid * 16 + (lane >> 4) * 4 + j;
      int d = fr + 16 * nf;
      out[((size_t)(b * SEQ) + r) * CH + h * HD + d] = __float2bfloat16(oacc[nf][j] * inv[j]);
    }
}

extern "C" void kernel_launch(void* const* d_in, const int* in_sizes, int n_in,
                              void* d_out, int out_size, void* d_ws, size_t ws_size,
                              hipStream_t stream) {
  const float* x_in  = (const float*)d_in[0];
  const float* y_in  = (const float*)d_in[1];
  const float* n1g   = (const float*)d_in[2];
  const float* n1b   = (const float*)d_in[3];
  const float* n2g   = (const float*)d_in[4];
  const float* n2b   = (const float*)d_in[5];
  const float* projw = (const float*)d_in[6];
  const float* projb = (const float*)d_in[7];
  const float* fc1w  = (const float*)d_in[8];
  const float* fc1b  = (const float*)d_in[9];
  const float* fc2w  = (const float*)d_in[10];
  const float* fc2b  = (const float*)d_in[11];
  // d_in[12] = is_selfatt (1 for the benchmarked inputs)

  char* p = (char*)d_ws;
  auto alloc = [&](size_t bytes) {
    char* r = p;
    p += (bytes + 255) & ~(size_t)255;
    return r;
  };
  float* xybuf  = (float*)alloc((size_t)MROWS * CH * 4);           // 16 MB
  float* x1y1   = (float*)alloc((size_t)MROWS * CH * 4);           // 16 MB
  bf16*  ln1out = (bf16*)alloc((size_t)MROWS * CH * 2);            // 8 MB
  bf16*  ln2out = (bf16*)alloc((size_t)MROWS * CH * 2);            // 8 MB
  bf16*  vTall  = (bf16*)alloc((size_t)2 * BHTOT * HD * SEQ * 2);  // 8 MB
  bf16*  attnout= (bf16*)alloc((size_t)MROWS * CH * 2);            // 8 MB
  bf16*  hbuf   = (bf16*)alloc((size_t)MROWS * HIDN * 2);          // 32 MB
  bf16*  projWT = (bf16*)alloc((size_t)CH * CH * 2);
  bf16*  fc1WT  = (bf16*)alloc((size_t)HIDN * CH * 2);
  bf16*  fc2WT  = (bf16*)alloc((size_t)CH * HIDN * 2);
  if ((size_t)(p - (char*)d_ws) > ws_size) return;

  float* outxy = (float*)d_out;  // merged [4096][1024] = x1 rows then y1 rows

  hipMemcpyAsync(xybuf, x_in, (size_t)ROWS * CH * 4, hipMemcpyDeviceToDevice, stream);
  hipMemcpyAsync(xybuf + (size_t)ROWS * CH, y_in, (size_t)ROWS * CH * 4,
                 hipMemcpyDeviceToDevice, stream);

  wt_transpose_kernel<<<dim3(CH / 32, CH / 32), 256, 0, stream>>>(projw, projWT, CH, CH);
  wt_transpose_kernel<<<dim3(CH / 32, HIDN / 32), 256, 0, stream>>>(fc1w, fc1WT, CH, HIDN);
  wt_transpose_kernel<<<dim3(HIDN / 32, CH / 32), 256, 0, stream>>>(fc2w, fc2WT, HIDN, CH);

  // one attention launch covers BOTH streams (bh 0..127); xorb=4 -> cross kv
  auto attn_all = [&](int xorb) {
    attn_fused<<<dim3(SEQ / 128, 2 * BHTOT), 512, 0, stream>>>(ln1out, vTall, attnout, xorb);
  };
  auto proj_merged = [&](const float* rbase, float* dst) {
    gemm128<0, 4><<<dim3(MROWS / 128, CH / 128), 256, 0, stream>>>(
        attnout, CH, projWT, CH, dst, CH, rbase, projb, CH);
  };
  auto mlp_merged = [&](const float* bsrc, float* dst) {
    ln_bf16_kernel<<<MROWS, 256, 0, stream>>>(bsrc, n2g, n2b, ln2out);
    gemm128<3, 3><<<dim3(MROWS / 128, HIDN / 128), 256, 0, stream>>>(
        ln2out, CH, fc1WT, CH, hbuf, HIDN, nullptr, fc1b, CH);
    gemm128<0, 4><<<dim3(MROWS / 128, CH / 128), 256, 0, stream>>>(
        hbuf, HIDN, fc2WT, HIDN, dst, CH, bsrc, fc2b, HIDN);
  };

  // 4 iterations of the self branch (x and y evolve only through this);
  // the cross branch's x1/y1 are dead except in the final iteration.
  for (int it = 0; it < 4; ++it) {
    ln_bf16_kernel<<<MROWS, 256, 0, stream>>>(xybuf, n1g, n1b, ln1out);
    head_transpose_kernel<<<dim3(SEQ / 32, HD / 32, 2 * BHTOT), 256, 0, stream>>>(ln1out, vTall);
    attn_all(0);
    proj_merged(xybuf, xybuf);
    mlp_merged(xybuf, xybuf);
  }
  // final cross blocks: x1 = x + attn(xn, yn, yn); y1 = y + attn(yn, xn, xn)
  ln_bf16_kernel<<<MROWS, 256, 0, stream>>>(xybuf, n1g, n1b, ln1out);
  head_transpose_kernel<<<dim3(SEQ / 32, HD / 32, 2 * BHTOT), 256, 0, stream>>>(ln1out, vTall);
  attn_all(4);
  proj_merged(xybuf, x1y1);
  mlp_merged(x1y1, outxy);
}